// Round 17
// baseline (467.702 us; speedup 1.0000x reference)
//
#include <hip/hip_runtime.h>

#define Bq 8
#define Fq 16
#define Nq 1024
#define Eq 256
#define Tq 64
constexpr float ALPHAq = 0.2f;
constexpr float LOG2Eq = 1.4426950408889634f;
constexpr int NNZCAP = 32768;       // global CSR allocation cap (actual nnz ~13.4K)
constexpr int MAXJE  = 20;          // edge-side entries/thread in regs (deg<=80); tail covers rest
constexpr int NNZW2  = 20480;       // padded node-major wvl data slots (actual ~15K)
constexpr int DUMP0  = NNZW2;       // 1024 dump slots for sentinel writes
constexpr int WVLTOT = NNZW2 + 1024;

// LDS-only barrier: drain lgkmcnt, NOT vmcnt -- the out-store and xnext-load
// are thread-private, so VMEM may float across. All inter-thread dataflow in
// k_recur is LDS (xnl/epp/wvl), which this orders correctly. "memory" clobbers
// on both sides pin all memory ops (incl. ds_*) against compiler motion.
// (Round-10 bundled this with factored-Z which NaN'd; rounds 11-12 proved
// factored-Z was the culprit -- this is the isolated retest.)
#define BAR() do { asm volatile("s_waitcnt lgkmcnt(0)" ::: "memory"); \
                   __builtin_amdgcn_s_barrier();                      \
                   asm volatile("" ::: "memory"); } while (0)

// raw v_exp_f32 (base-2 exp), no OCML denormal fixup (round-14 lesson).
__device__ __forceinline__ float fast_exp2(float x) {
  return __builtin_amdgcn_exp2f(x);
}

// quad-lane exchanges on the VALU pipe (DPP).
__device__ __forceinline__ float qswap1(float x) {
  return __int_as_float(__builtin_amdgcn_mov_dpp(__float_as_int(x), 0xB1, 0xF, 0xF, true));
}
__device__ __forceinline__ float qswap2(float x) {
  return __int_as_float(__builtin_amdgcn_mov_dpp(__float_as_int(x), 0x4E, 0xF, 0xF, true));
}

// parallel exclusive scan over 1024 values (Hillis-Steele in LDS); also returns total
__device__ __forceinline__ int scan_excl_1024(int* s, int tid, int val, int* total) {
  __syncthreads();                  // protect s reuse across calls
  s[tid] = val;
  __syncthreads();
  for (int d = 1; d < 1024; d <<= 1) {
    int t = s[tid];
    if (tid >= d) t += s[tid - d];
    __syncthreads();
    s[tid] = t;
    __syncthreads();
  }
  *total = s[1023];
  return s[tid] - val;
}

// ---------- counts: edge counts per rowblock + node counts (coalesced) ----------
__global__ __launch_bounds__(256) void k_cntB(const float* __restrict__ inc,
                                              int* __restrict__ gcnt,
                                              int* __restrict__ ncnt) {
  __shared__ int cp[64][4];
  const int i = blockIdx.x, tid = threadIdx.x;
  {
    const int e = tid, base = i * 64;
    int c = 0;
    for (int r = 0; r < 64; ++r) c += (inc[(size_t)(base + r) * Eq + e] > 0.f) ? 1 : 0;
    gcnt[i * Eq + e] = c;
  }
  const int nl = tid >> 2, kc = tid & 3, n = i * 64 + nl;
  {
    const float4* r4 = (const float4*)(inc + (size_t)n * Eq + kc * 64);
    int c = 0;
    for (int j = 0; j < 16; ++j) {
      const float4 v = r4[j];
      c += (v.x > 0.f) + (v.y > 0.f) + (v.z > 0.f) + (v.w > 0.f);
    }
    cp[nl][kc] = c;
  }
  __syncthreads();
  if (kc == 0) ncnt[n] = cp[nl][0] + cp[nl][1] + cp[nl][2] + cp[nl][3];
}

// ---------- prefixes: parallel scans ----------
__global__ __launch_bounds__(1024) void k_prefB(const int* __restrict__ gcnt,
                                                const int* __restrict__ ncnt,
                                                int* __restrict__ g_ptr,
                                                int* __restrict__ goff,
                                                int* __restrict__ tlp,
                                                int* __restrict__ tlp2) {
  __shared__ int s[1024];
  const int tid = threadIdx.x;
  int tot;
  int tote = 0;
  if (tid < Eq) for (int i = 0; i < 16; ++i) tote += gcnt[i * Eq + tid];
  const int exE = scan_excl_1024(s, tid, (tid < Eq) ? tote : 0, &tot);
  if (tid < Eq) {
    g_ptr[tid] = exE;
    int run = exE;
    for (int i = 0; i < 16; ++i) { goff[i * Eq + tid] = run; run += gcnt[i * Eq + tid]; }
  }
  if (tid == 0) g_ptr[Eq] = tot;
  const int dn = ncnt[tid];
  const int exN = scan_excl_1024(s, tid, dn, &tot);
  tlp[tid] = exN;
  if (tid == 0) tlp[Nq] = tot;
  const int dp = (dn + 3) & ~3;
  const int exP = scan_excl_1024(s, tid, dp, &tot);
  tlp2[tid] = exP;
  if (tid == 0) tlp2[Nq] = tot;
}

// ---------- fills: edge-CSR node list + node-side rank8 map ----------
__global__ __launch_bounds__(256) void k_fillB(const float* __restrict__ inc,
                                               const int* __restrict__ goff,
                                               unsigned short* __restrict__ g_nodes,
                                               unsigned char* __restrict__ rank8) {
  __shared__ int cp[64][4];
  const int i = blockIdx.x, tid = threadIdx.x;
  {
    const int e = tid, base = i * 64;
    int w = goff[i * Eq + e];
    for (int r = 0; r < 64; ++r) {
      const int n = base + r;
      if (inc[(size_t)n * Eq + e] > 0.f) { if (w < NNZCAP) g_nodes[w] = (unsigned short)n; ++w; }
    }
  }
  const int nl = tid >> 2, kc = tid & 3, n = i * 64 + nl;
  const float* row = inc + (size_t)n * Eq + kc * 64;
  {
    const float4* r4 = (const float4*)row;
    int c = 0;
    for (int j = 0; j < 16; ++j) {
      const float4 v = r4[j];
      c += (v.x > 0.f) + (v.y > 0.f) + (v.z > 0.f) + (v.w > 0.f);
    }
    cp[nl][kc] = c;
  }
  __syncthreads();
  {
    int base = 0;
    for (int c2 = 0; c2 < kc; ++c2) base += cp[nl][c2];
    int r = base;
    for (int k = 0; k < 64; ++k)
      if (row[k] > 0.f) { rank8[(size_t)n * Eq + kc * 64 + k] = (unsigned char)r; ++r; }
  }
}

// ---------- prep: packed (wpos2<<16 | n) per-thread table + padded wpos map ----------
__global__ __launch_bounds__(256) void k_prep(const int* __restrict__ g_ptr,
                                              const unsigned short* __restrict__ g_nodes,
                                              const int* __restrict__ tlp2_g,
                                              const unsigned char* __restrict__ rank8,
                                              unsigned* __restrict__ tbl_g,
                                              unsigned short* __restrict__ wpos_g) {
  const int t = blockIdx.x * 256 + threadIdx.x;   // 0..1023 (e = t>>2, sub = t&3)
  const int e = t >> 2, sub = t & 3;
  const int p0 = g_ptr[e], p1 = g_ptr[e + 1];
  int j = 0;
  for (int pos = p0 + sub; pos < p1; pos += 4, ++j) {
    const int n = (int)g_nodes[pos];
    int wp = tlp2_g[n] + (int)rank8[(size_t)n * Eq + e];
    if (wp >= NNZW2) wp = DUMP0 + t;               // defensive clamp
    wpos_g[pos] = (unsigned short)wp;
    if (j < MAXJE) tbl_g[j * Nq + t] = ((unsigned)wp << 16) | (unsigned)n;
  }
  for (; j < MAXJE; ++j)
    tbl_g[j * Nq + t] = ((unsigned)(DUMP0 + t) << 16) | (unsigned)Nq;   // sentinel
}

// ---------- static node projection for all timesteps ----------
__global__ __launch_bounds__(256) void k_xnp(const float* __restrict__ x,
                                             const float* __restrict__ mask,
                                             const float* __restrict__ weight,
                                             const float* __restrict__ bias,
                                             float* __restrict__ xnpT) {
  __shared__ float accs[64][65];
  const int wg = blockIdx.x;
  const int b = wg >> 4;
  const int n0 = (wg & 15) << 6;
  const int lane = threadIdx.x & 63;
  const int w = threadIdx.x >> 6;
  float a[16];
#pragma unroll
  for (int i = 0; i < 16; ++i) a[i] = 0.f;
  for (int f = 0; f < Fq; ++f) {
    const float wf = weight[f], wm = weight[Fq + f];
#pragma unroll
    for (int ii = 0; ii < 16; ++ii) {
      const int i = w + ii * 4;
      const size_t base = ((size_t)(b * Fq + f) * Nq + n0 + i) * Tq + lane;
      a[ii] += x[base] * wf + mask[base] * wm;
    }
  }
#pragma unroll
  for (int ii = 0; ii < 16; ++ii) accs[w + ii * 4][lane] = a[ii];
  __syncthreads();
  const float bl = bias[n0 + lane];
#pragma unroll
  for (int jj = 0; jj < 16; ++jj) {
    const int tt = w + jj * 4;
    xnpT[((size_t)b * Tq + tt) * Nq + n0 + lane] = accs[lane][tt] + bl;
  }
}

// ---------- full 64-step recurrence: one block per batch ----------
// Round-16 math byte-identical; ONLY change: lgkm-only BAR() barriers so the
// out-store / xnext-load are not drained 3x per step (isolated retest of the
// round-10 barrier idea, exonerated by the round-11/12 bisection).
__global__ __attribute__((amdgpu_flat_work_group_size(1024, 1024), amdgpu_waves_per_eu(4, 4)))
void k_recur(
    const float* __restrict__ xnpT, const float* __restrict__ w2,
    const int* __restrict__ g_ptr, const unsigned short* __restrict__ g_nodes,
    const unsigned short* __restrict__ wpos_g,
    const int* __restrict__ tlp_g, const int* __restrict__ tlp2_g,
    const unsigned* __restrict__ tbl_g,
    const float* __restrict__ h0,
    const float* __restrict__ weight, const float* __restrict__ a_vec,
    float* __restrict__ out) {
  __shared__ __align__(16) float wvl[WVLTOT];   // 86KB padded node-major attn*edge (+dump)
  __shared__ float xnl[Nq + 4];                 // xn this step; [1024] = 0 sentinel
  __shared__ __align__(16) float epp[4 * 72];   // edge_pre, bank-padded (stride 72)

  const int b = blockIdx.x;
  const int tid = threadIdx.x;
  const int e = tid >> 2;                       // 256 edges, 4 threads each
  const int sub = tid & 3;
  const float w32 = weight[2 * Fq];
  const float a0 = a_vec[0], a1 = a_vec[1];
  const float a0L = a0 * LOG2Eq;                // base-2-domain slope

  for (int i = tid; i < WVLTOT; i += 1024) wvl[i] = 0.f;

  float xn_reg = xnpT[(size_t)b * Tq * Nq + tid] + w32 * h0[tid];
  xnl[tid] = xn_reg;
  if (tid == 0) xnl[Nq] = 0.f;                  // pass1 sentinel

  unsigned uj[MAXJE];
#pragma unroll
  for (int j = 0; j < MAXJE; ++j) uj[j] = tbl_g[j * Nq + tid];

  float w2r[64];
#pragma unroll
  for (int kk = 0; kk < 64; ++kk)
    w2r[kk] = w2[(size_t)(sub * 64 + kk) * Eq + e];

  const int p0 = g_ptr[e], p1 = g_ptr[e + 1];
  const float degf = (float)(p1 - p0);
  const int tail0 = p0 + sub + 4 * MAXJE;       // edge-side tail start (deg>80 only)
  const int q0v = tlp2_g[tid] >> 2;             // my node's first float4 slot
  const int degn = tlp_g[tid + 1] - tlp_g[tid];
  const int iters = (tid == 0) ? 0 : ((degn + 3) >> 2);   // node0 via wave-0 reduce
  BAR();                                        // xnl + wvl zeros ready (LDS-only)

  float xv[MAXJE];

  for (int t = 0; t < Tq; ++t) {
    const float xnext = xnpT[((size_t)b * Tq + (t + 1 < Tq ? t + 1 : t)) * Nq + tid];

    // ---- pass1: gather incident xn; edge_pre partial; running max (monotonicity) ----
    float v = 0.f;
    float mxv = -3.0e38f;
#pragma unroll
    for (int j = 0; j < MAXJE; ++j) {
      const int n = (int)(uj[j] & 0xffffu);
      const float xx = xnl[n];                  // sentinel n=1024 -> 0
      v += xx;
      const float val = (n < Nq) ? xx : -1.0e30f;
      xv[j] = val;
      mxv = fmaxf(mxv, val);
    }
    for (int pos = tail0; pos < p1; pos += 4) {
      const float xx = xnl[(int)g_nodes[pos]];
      v += xx;
      mxv = fmaxf(mxv, xx);
    }
    v += qswap1(v);
    v += qswap2(v);
    mxv = fmaxf(mxv, qswap1(mxv));
    mxv = fmaxf(mxv, qswap2(mxv));
    if (sub == 0) epp[(e >> 6) * 72 + (e & 63)] = v / degf;
    BAR();  // S1: ep complete

    // ---- mat-vec: edge2 = ep @ w2 (register w2, bank-padded b128 ep reads) ----
    float acc = 0.f;
#pragma unroll
    for (int k = 0; k < 16; ++k) {
      const float4 epv = *reinterpret_cast<const float4*>(&epp[sub * 72 + (k << 2)]);
      acc += w2r[k * 4 + 0] * epv.x + w2r[k * 4 + 1] * epv.y +
             w2r[k * 4 + 2] * epv.z + w2r[k * 4 + 3] * epv.w;
    }
    acc += qswap1(acc);
    acc += qswap2(acc);
    const float edge2 = acc;                    // time_e cancels in the softmax ratio
    const float e2a1L = (edge2 * a1) * LOG2Eq;
    const float sm2 = mxv * a0L + e2a1L;
    const float mx2 = fmaxf(sm2, ALPHAq * sm2);

    // ---- Z; overwrite xv with exp2 (correlated rounding: arg <= 0 in floats) ----
    float Zs = 0.f;
#pragma unroll
    for (int j = 0; j < MAXJE; ++j) {
      const float s2 = xv[j] * a0L + e2a1L;
      const float p = fast_exp2(fmaxf(s2, ALPHAq * s2) - mx2);
      xv[j] = p;
      Zs += p;
    }
    for (int pos = tail0; pos < p1; pos += 4) {
      const float s2 = xnl[(int)g_nodes[pos]] * a0L + e2a1L;
      Zs += fast_exp2(fmaxf(s2, ALPHAq * s2) - mx2);
    }
    Zs += qswap1(Zs);
    Zs += qswap2(Zs);
    const float we = edge2 / Zs;

    // ---- write attn*edge into padded node-major wvl (sentinels -> dump, write 0) ----
#pragma unroll
    for (int j = 0; j < MAXJE; ++j)
      wvl[uj[j] >> 16] = xv[j] * we;
    for (int pos = tail0; pos < p1; pos += 4) {
      const float s2 = xnl[(int)g_nodes[pos]] * a0L + e2a1L;
      wvl[(int)wpos_g[pos]] = fast_exp2(fmaxf(s2, ALPHAq * s2) - mx2) * we;
    }
    BAR();  // S2: wvl complete

    // ---- node side: b128 sums over my padded run; node0 via wave-0 reduce ----
    float nv = 0.f;
    if (tid < 64) {                             // wvl[0..255] = node0's slots
      const float4 w4 = reinterpret_cast<const float4*>(wvl)[tid];
      float q = w4.x + w4.y + w4.z + w4.w;
#pragma unroll
      for (int m = 32; m > 0; m >>= 1) q += __shfl_xor(q, m);
      if (tid == 0) nv = q;
    }
    for (int i = 0; i < iters; ++i) {
      const float4 w4 = reinterpret_cast<const float4*>(wvl)[q0v + i];
      nv += w4.x + w4.y + w4.z + w4.w;          // pad slots are exactly 0
    }

    // ---- epilogue: write out, advance xn ----
    out[((size_t)b * Tq + t) * Nq + tid] = nv;
    xn_reg = xnext + w32 * nv;
    xnl[tid] = xn_reg;
    BAR();  // S3: xnl ready for next step (out-store NOT drained)
  }
}

extern "C" void kernel_launch(void* const* d_in, const int* in_sizes, int n_in,
                              void* d_out, int out_size, void* d_ws, size_t ws_size,
                              hipStream_t stream) {
  (void)in_sizes; (void)n_in; (void)out_size; (void)ws_size;
  const float* x      = (const float*)d_in[0];
  const float* mask   = (const float*)d_in[1];
  const float* inc    = (const float*)d_in[2];
  const float* h0     = (const float*)d_in[3];
  const float* bias   = (const float*)d_in[5];
  const float* weight = (const float*)d_in[6];
  const float* w2     = (const float*)d_in[7];
  const float* avec   = (const float*)d_in[8];
  float* out = (float*)d_out;

  char* ws = (char*)d_ws;
  size_t off = 0;
  auto alloc = [&](size_t bytes) { void* p = ws + off; off += (bytes + 255) & ~(size_t)255; return p; };
  int*            g_ptr   = (int*)alloc((Eq + 1) * 4);
  int*            gcnt    = (int*)alloc(16 * Eq * 4);
  int*            goff    = (int*)alloc(16 * Eq * 4);
  unsigned short* g_nodes = (unsigned short*)alloc((size_t)NNZCAP * 2);
  int*            ncnt    = (int*)alloc(Nq * 4);
  int*            tlp_g   = (int*)alloc((Nq + 1) * 4);
  int*            tlp2_g  = (int*)alloc((Nq + 1) * 4);
  unsigned char*  rank8   = (unsigned char*)alloc((size_t)Nq * Eq);
  unsigned short* wpos_g  = (unsigned short*)alloc((size_t)NNZCAP * 2);
  unsigned*       tbl_g   = (unsigned*)alloc((size_t)MAXJE * Nq * 4);
  float*          xnpT    = (float*)alloc((size_t)Bq * Tq * Nq * 4);

  k_cntB <<<16, 256, 0, stream>>>(inc, gcnt, ncnt);
  k_prefB<<<1, 1024, 0, stream>>>(gcnt, ncnt, g_ptr, goff, tlp_g, tlp2_g);
  k_fillB<<<16, 256, 0, stream>>>(inc, goff, g_nodes, rank8);
  k_prep <<<4, 256, 0, stream>>>(g_ptr, g_nodes, tlp2_g, rank8, tbl_g, wpos_g);
  k_xnp  <<<128, 256, 0, stream>>>(x, mask, weight, bias, xnpT);
  k_recur<<<Bq, 1024, 0, stream>>>(xnpT, w2, g_ptr, g_nodes, wpos_g, tlp_g, tlp2_g,
                                   tbl_g, h0, weight, avec, out);
}